// Round 1
// 27.737 us; speedup vs baseline: 1.0414x; 1.0414x over previous
//
#include <hip/hip_runtime.h>
#include <math.h>

// Problem constants (from reference): B=16, T=4096, C=80, K=32
#define CC 80
#define KK 32
#define STRIDE 33                    // 32 sorted entries + 1 sentinel per channel
#define NTOT (16 * 4096 * 80)        // 5,242,880 elements
#define BLOCK 256
#define GRID 1280                    // 1280*256 = 327,680 threads, multiple of 80
#define NTHREADS (GRID * BLOCK)
#define EPT (NTOT / NTHREADS)        // 16 elements per thread, exact, no tail

// Sorted centroid entry: value + original k (for exact first-index tie-break).
struct Entry { float v; int idx; };

// ---------------------------------------------------------------------------
// Prep: stable-sort each channel's 32 centroids by value (rank counting — no
// actual sort, each thread computes its element's rank). Runs once per launch,
// 2560 threads, ~1 us. Sentinel entry [32] = +inf so the main kernel's
// bracketing fetch needs no clamping on the high side.
// ---------------------------------------------------------------------------
__global__ void prep_kernel(const float* __restrict__ cent,
                            Entry* __restrict__ es) {
    const int t = blockIdx.x * blockDim.x + threadIdx.x;
    if (t >= CC * KK) return;
    const int c = t >> 5;   // t / 32
    const int k = t & 31;   // t % 32
    const float* row = cent + c * KK;
    const float v = row[k];
    int rank = 0;
#pragma unroll
    for (int j = 0; j < KK; ++j) {
        const float w = row[j];
        // stable: strictly smaller value, or equal value with smaller index
        rank += (int)(w < v) | ((int)(w == v) & (int)(j < k));
    }
    es[c * STRIDE + rank].v = v;
    es[c * STRIDE + rank].idx = k;
    if (k == 0) {
        es[c * STRIDE + 32].v = INFINITY;      // sentinel: never wins
        es[c * STRIDE + 32].idx = 0x7fffffff;
    }
}

// ---------------------------------------------------------------------------
// Main: each thread owns a fixed channel c = tid % 80. Sorted values live in
// VGPRs; per element, count how many sorted values are <= x (two independent
// add chains -> short dependence depth), then fetch the two bracketing
// (value, orig_idx) entries from LDS and do the exact distance compare with
// jnp.argmin's first-index tie-break.
//
// Exactness: fl(|x-c|) is monotone in the real distance on each side of x, so
// the global fl-argmin is one of the two bracketing sorted neighbors; the only
// tie between far-apart values (midpoint tie) is lo-vs-hi and is resolved by
// original index, matching the reference bitwise.
// ---------------------------------------------------------------------------
__global__ __launch_bounds__(BLOCK) void discretize_kernel(
    const float* __restrict__ mel,
    const Entry* __restrict__ es,
    float* __restrict__ out) {
    __shared__ alignas(16) Entry se[CC * STRIDE];   // 2640 * 8B = 21,120 B

    // Stage sorted tables to LDS, 16B per lane, coalesced. 2640*8/16 = 1320.
    const int t = threadIdx.x;
    {
        const ulong2* src = (const ulong2*)es;
        ulong2* dst = (ulong2*)se;
        for (int i = t; i < (CC * STRIDE) / 2; i += BLOCK) dst[i] = src[i];
    }
    __syncthreads();

    const int tid = blockIdx.x * BLOCK + t;
    const int c = tid % CC;           // fixed for all EPT elements of this thread
    const Entry* ch = se + c * STRIDE;

    // Sorted values into VGPRs (static indices -> registers).
    float sv[KK];
#pragma unroll
    for (int k = 0; k < KK; ++k) sv[k] = ch[k].v;

#pragma unroll 4
    for (int i = 0; i < EPT; ++i) {
        const int e = tid + i * NTHREADS;
        const float x = mel[e];

        // insertion count: #{ sorted values <= x }, two parallel chains
        int cA = 0, cB = 0;
#pragma unroll
        for (int k = 0; k < KK; k += 2) {
            cA += (int)(sv[k]     <= x);
            cB += (int)(sv[k + 1] <= x);
        }
        int lo = cA + cB - 1;
        lo = lo < 0 ? 0 : lo;         // cnt==0 -> compare (s0, s1): s0 wins exactly

        // bracketing pair (lo, lo+1); lo+1 <= 32 hits the +inf sentinel
        const Entry e0 = ch[lo];
        const Entry e1 = ch[lo + 1];

        const float dlo = fabsf(x - e0.v);
        const float dhi = fabsf(x - e1.v);
        // strict <, plus first-original-index wins on exact fl-distance tie
        const bool hi = (dhi < dlo) | ((dhi == dlo) & (e1.idx < e0.idx));
        out[e] = hi ? e1.v : e0.v;
    }
}

extern "C" void kernel_launch(void* const* d_in, const int* in_sizes, int n_in,
                              void* d_out, int out_size, void* d_ws, size_t ws_size,
                              hipStream_t stream) {
    const float* mel = (const float*)d_in[0];   // (B,T,C) f32
    const float* cent = (const float*)d_in[1];  // (C,K) f32
    float* out = (float*)d_out;                 // (B,T,C) f32
    Entry* es = (Entry*)d_ws;                   // 80*33*8 = 21,120 B of workspace

    prep_kernel<<<(CC * KK + BLOCK - 1) / BLOCK, BLOCK, 0, stream>>>(cent, es);
    discretize_kernel<<<GRID, BLOCK, 0, stream>>>(mel, es, out);
}